// Round 2
// baseline (1117.160 us; speedup 1.0000x reference)
//
#include <hip/hip_runtime.h>
#include <hip/hip_bf16.h>

// R1 post-mortem: NaN out => fused ran, produced NaN. Only consistent cause:
// inputs are fp32 read as bf16 (mantissa bits -> bf16 exponent -> NaN). But
// threshold/label hint bf16. Resolution: on-device dtype sniff, dual-path I/O,
// bf16 MFMA core either way.

#define NB 65536
#define XSTR 296   // LDS row stride (shorts) for X buffer
#define HSTR 264   // LDS row stride (shorts) for H buffers

typedef __attribute__((ext_vector_type(8))) short short8;
typedef __attribute__((ext_vector_type(4))) float f32x4;
typedef __attribute__((ext_vector_type(4))) int int4v;

__device__ __forceinline__ float bf2f(unsigned short u){
  union { unsigned int i; float f; } x; x.i = ((unsigned int)u) << 16; return x.f;
}
__device__ __forceinline__ unsigned short f2bf(float f){
  unsigned int x = __float_as_uint(f);
  x += 0x7fffu + ((x >> 16) & 1u);   // RNE
  return (unsigned short)(x >> 16);
}

struct KParams {
  const void* obs;
  const void* act;
  const unsigned short* w1t[2];
  const unsigned short* w2t[2];
  const unsigned short* w3t[2];
  const void* b1[2];
  const void* b2[2];
  const void* b3[2];
  const void* w4[2];
  const void* b4[2];
  const int* counts;
  const int* perm;
  const int* flag;
  void* out;
};

// ---- dtype sniff: low short of each 4-byte group. bf16 data -> valid exponents;
// fp32 data -> random mantissa bits, ~9% in-range. ----
__global__ void sniff_kernel(const void* obs, int* flag){
  int lane = threadIdx.x;
  unsigned short u = ((const unsigned short*)obs)[lane * 2];
  int e = (u >> 7) & 0xFF;
  int ok = (e >= 110 && e <= 132) ? 1 : 0;
  unsigned long long m = __ballot(ok);
  if (lane == 0) flag[0] = (__popcll(m) >= 32) ? 1 : 0;
}

__device__ __forceinline__ float ldval(const void* p, int idx, int isbf16){
  return isbf16 ? bf2f(((const unsigned short*)p)[idx]) : ((const float*)p)[idx];
}

// ---- weight prep: [t][k][n] -> bf16 [t][n][k], W1 K padded 264->288 ----
__global__ void prep_kernel(const void* q1W1, const void* q1W2, const void* q1W3,
                            const void* q2W1, const void* q2W2, const void* q2W3,
                            const int* flag, unsigned short* out){
  int isbf16 = flag[0];
  int gid = blockIdx.x * 256 + threadIdx.x;
  int net = gid / 614400;
  if (net >= 2) return;
  int idx = gid - net * 614400;
  const void* W1 = net ? q2W1 : q1W1;
  const void* W2 = net ? q2W2 : q1W2;
  const void* W3 = net ? q2W3 : q1W3;
  unsigned short* o = out + net * 614400;
  float v = 0.f;
  if (idx < 221184) {                      // W1t: [3][256][288]
    int t = idx / 73728; int rem = idx - t * 73728;
    int n = rem / 288;   int k = rem - n * 288;
    v = (k < 264) ? ldval(W1, (t * 264 + k) * 256 + n, isbf16) : 0.f;
  } else if (idx < 417792) {               // W2t: [3][256][256]
    int j = idx - 221184;
    int t = j >> 16; int rem = j & 65535;
    int n = rem >> 8; int k = rem & 255;
    v = ldval(W2, (t << 16) + (k << 8) + n, isbf16);
  } else {                                 // W3t: [3][256][256]
    int j = idx - 417792;
    int t = j >> 16; int rem = j & 65535;
    int n = rem >> 8; int k = rem & 255;
    v = ldval(W3, (t << 16) + (k << 8) + n, isbf16);
  }
  o[idx] = f2bf(v);
}

// ---- routing: EXACT input precision (downcast could flip argmax) ----
__device__ __forceinline__ int task_of(const void* obs, int b, int isbf16){
  float v0 = ldval(obs, b * 256 + 253, isbf16);
  float v1 = ldval(obs, b * 256 + 254, isbf16);
  float v2 = ldval(obs, b * 256 + 255, isbf16);
  int t = 0; float m = v0;
  if (v1 > m) { m = v1; t = 1; }   // strict > => first-occurrence argmax (jnp semantics)
  if (v2 > m) { t = 2; }
  return t;
}

__global__ void route_count(const void* __restrict__ obs, const int* flag, int* counts){
  int isbf16 = flag[0];
  int b = blockIdx.x * 256 + threadIdx.x;
  atomicAdd(&counts[task_of(obs, b, isbf16)], 1);
}

__global__ void route_scatter(const void* __restrict__ obs, const int* flag, const int* counts,
                              int* cursors, int* perm){
  int isbf16 = flag[0];
  int b = blockIdx.x * 256 + threadIdx.x;
  int t = task_of(obs, b, isbf16);
  int c0 = counts[0], c1 = counts[1];
  int off = (t == 0) ? 0 : (t == 1) ? ((c0 + 63) & ~63)
                                    : ((c0 + 63) & ~63) + ((c1 + 63) & ~63);
  int pos = atomicAdd(&cursors[t], 1);
  perm[off + pos] = b;
}

// ---- fused 4-layer routed MLP, one 64-row task-uniform tile per block ----
__global__ __launch_bounds__(256, 2) void fused_kernel(KParams p){
  __shared__ unsigned short X[64 * XSTR];   // 37,888 B ; reused as HB after layer 1
  __shared__ unsigned short HA[64 * HSTR];  // 33,792 B
  unsigned short* HB = X;

  int tid = threadIdx.x;
  int net = blockIdx.y;
  int p0  = blockIdx.x * 64;
  int isbf16 = p.flag[0];
  int c0 = p.counts[0], c1 = p.counts[1];
  int off1 = (c0 + 63) & ~63;
  int off2 = off1 + ((c1 + 63) & ~63);
  int task = (p0 >= off2) ? 2 : ((p0 >= off1) ? 1 : 0);

  // stage X tile: 64 rows x 33 chunks of 8 elements (32 obs + 1 action chunk)
  for (int idx = tid; idx < 64 * 33; idx += 256) {
    int row = idx / 33; int c = idx - row * 33;
    int r = p.perm[p0 + row];
    short8 sv = {0,0,0,0,0,0,0,0};
    if (r >= 0) {
      if (isbf16) {
        const unsigned short* src = (c < 32) ? ((const unsigned short*)p.obs + r * 256 + c * 8)
                                             : ((const unsigned short*)p.act + r * 8);
        sv = *(const short8*)src;
      } else {
        const float* src = (c < 32) ? ((const float*)p.obs + r * 256 + c * 8)
                                    : ((const float*)p.act + r * 8);
        f32x4 a = *(const f32x4*)src;
        f32x4 b = *(const f32x4*)(src + 4);
        #pragma unroll
        for (int j = 0; j < 4; j++) { sv[j] = (short)f2bf(a[j]); sv[4 + j] = (short)f2bf(b[j]); }
      }
    }
    *(short8*)(X + row * XSTR + c * 8) = sv;
  }
  // zero K-pad cols 264..287
  for (int idx = tid; idx < 64 * 3; idx += 256) {
    int row = idx / 3; int c = idx - row * 3;
    short8 z = {0,0,0,0,0,0,0,0};
    *(short8*)(X + row * XSTR + 264 + c * 8) = z;
  }
  __syncthreads();

  int wave = tid >> 6, lane = tid & 63, quad = lane >> 4, l16 = lane & 15;
  int nbase = wave * 64;   // each wave owns 64 output cols

  auto run_layer = [&](const unsigned short* lin, int lstride,
                       const unsigned short* wt, int K,
                       const void* bias, unsigned short* lout){
    f32x4 acc[4][4];
    f32x4 z = {0.f, 0.f, 0.f, 0.f};
    for (int mt = 0; mt < 4; mt++) for (int nt = 0; nt < 4; nt++) acc[mt][nt] = z;
    int kc = K >> 5;
    for (int kb = 0; kb < kc; ++kb) {
      int ko = (kb << 5) + quad * 8;
      short8 bfr[4], afr[4];
      #pragma unroll
      for (int nt = 0; nt < 4; nt++)          // B-frags from global (L2-hot)
        bfr[nt] = *(const short8*)(wt + (nbase + nt * 16 + l16) * K + ko);
      #pragma unroll
      for (int mt = 0; mt < 4; mt++)          // A-frags from LDS
        afr[mt] = *(const short8*)(lin + (mt * 16 + l16) * lstride + ko);
      #pragma unroll
      for (int mt = 0; mt < 4; mt++)
        #pragma unroll
        for (int nt = 0; nt < 4; nt++)
          acc[mt][nt] = __builtin_amdgcn_mfma_f32_16x16x32_bf16(afr[mt], bfr[nt], acc[mt][nt], 0, 0, 0);
    }
    float bv[4];
    #pragma unroll
    for (int nt = 0; nt < 4; nt++) bv[nt] = ldval(bias, nbase + nt * 16 + l16, isbf16);
    #pragma unroll
    for (int mt = 0; mt < 4; mt++)
      #pragma unroll
      for (int nt = 0; nt < 4; nt++) {
        f32x4 a = acc[mt][nt];
        #pragma unroll
        for (int r = 0; r < 4; r++) {
          float v = fmaxf(a[r] + bv[nt], 0.f);   // C/D: col=lane&15, row=quad*4+r
          lout[(mt * 16 + quad * 4 + r) * HSTR + nbase + nt * 16 + l16] = f2bf(v);
        }
      }
    __syncthreads();
  };

  run_layer(X,  XSTR, p.w1t[net] + task * 73728, 288, (const char*)p.b1[net] + task * 256 * (isbf16 ? 2 : 4), HA);
  run_layer(HA, HSTR, p.w2t[net] + task * 65536, 256, (const char*)p.b2[net] + task * 256 * (isbf16 ? 2 : 4), HB);
  run_layer(HB, HSTR, p.w3t[net] + task * 65536, 256, (const char*)p.b3[net] + task * 256 * (isbf16 ? 2 : 4), HA);

  // layer 4: y = h3 . w4 + b4  (4 threads per row, shuffle-combine)
  int row = tid >> 2, seg = tid & 3;
  float s = 0.f;
  #pragma unroll
  for (int kk = 0; kk < 64; kk += 8) {
    short8 hv = *(const short8*)(HA + row * HSTR + seg * 64 + kk);
    float wv[8];
    if (isbf16) {
      const unsigned short* w4p = (const unsigned short*)p.w4[net] + task * 256 + seg * 64 + kk;
      short8 t = *(const short8*)w4p;
      #pragma unroll
      for (int j = 0; j < 8; j++) wv[j] = bf2f((unsigned short)t[j]);
    } else {
      const float* w4p = (const float*)p.w4[net] + task * 256 + seg * 64 + kk;
      f32x4 a = *(const f32x4*)w4p;
      f32x4 b = *(const f32x4*)(w4p + 4);
      #pragma unroll
      for (int j = 0; j < 4; j++) { wv[j] = a[j]; wv[4 + j] = b[j]; }
    }
    #pragma unroll
    for (int j = 0; j < 8; j++)
      s += bf2f((unsigned short)hv[j]) * wv[j];
  }
  s += __shfl_xor(s, 1);
  s += __shfl_xor(s, 2);
  if (seg == 0) {
    int r = p.perm[p0 + row];
    if (r >= 0) {
      float y = s + ldval(p.b4[net], task, isbf16);
      if (isbf16) ((unsigned short*)p.out)[net * NB + r] = f2bf(y);
      else        ((float*)p.out)[net * NB + r] = y;
    }
  }
}

extern "C" void kernel_launch(void* const* d_in, const int* in_sizes, int n_in,
                              void* d_out, int out_size, void* d_ws, size_t ws_size,
                              hipStream_t stream) {
  char* ws = (char*)d_ws;
  int* counts  = (int*)ws;                 // 3 ints @0
  int* cursors = (int*)(ws + 16);          // 3 ints @16
  int* flag    = (int*)(ws + 48);          // 1 int  @48
  int* perm    = (int*)(ws + 64);          // 65728 ints
  unsigned short* wts = (unsigned short*)(ws + 263168);  // 2 * 614400 bf16

  hipMemsetAsync(ws, 0, 64, stream);                 // counts + cursors + flag
  hipMemsetAsync(perm, 0xFF, 65728 * 4, stream);     // perm = -1 (pad sentinel)

  const void* obs = d_in[0];
  const void* act = d_in[1];

  sniff_kernel<<<1, 64, 0, stream>>>(obs, flag);
  prep_kernel<<<4800, 256, 0, stream>>>(d_in[2], d_in[4], d_in[6],
                                        d_in[10], d_in[12], d_in[14], flag, wts);
  route_count<<<256, 256, 0, stream>>>(obs, flag, counts);
  route_scatter<<<256, 256, 0, stream>>>(obs, flag, counts, cursors, perm);

  KParams kp;
  kp.obs = obs; kp.act = act;
  for (int q = 0; q < 2; q++) {
    int base = 2 + q * 8;
    kp.b1[q] = d_in[base + 1];
    kp.b2[q] = d_in[base + 3];
    kp.b3[q] = d_in[base + 5];
    kp.w4[q] = d_in[base + 6];
    kp.b4[q] = d_in[base + 7];
    kp.w1t[q] = wts + q * 614400;
    kp.w2t[q] = wts + q * 614400 + 221184;
    kp.w3t[q] = wts + q * 614400 + 417792;
  }
  kp.counts = counts; kp.perm = perm; kp.flag = flag;
  kp.out = d_out;

  fused_kernel<<<dim3(1027, 2), 256, 0, stream>>>(kp);
}

// Round 3
// 288.089 us; speedup vs baseline: 3.8778x; 3.8778x over previous
//
#include <hip/hip_runtime.h>
#include <hip/hip_bf16.h>

// R2 post-mortem: PASS, absmax 3.9e-3. But 834/1117 us was routing: 65536
// global atomicAdds on 3 addresses serialize (~12ns each). Fix: per-block LDS
// histogram + 3 global atomics/block (counting sort), task cached as bytes.

#define NB 65536
#define XSTR 296   // LDS row stride (shorts) for X buffer
#define HSTR 264   // LDS row stride (shorts) for H buffers

typedef __attribute__((ext_vector_type(8))) short short8;
typedef __attribute__((ext_vector_type(4))) float f32x4;

__device__ __forceinline__ float bf2f(unsigned short u){
  union { unsigned int i; float f; } x; x.i = ((unsigned int)u) << 16; return x.f;
}
__device__ __forceinline__ unsigned short f2bf(float f){
  unsigned int x = __float_as_uint(f);
  x += 0x7fffu + ((x >> 16) & 1u);   // RNE
  return (unsigned short)(x >> 16);
}

struct KParams {
  const void* obs;
  const void* act;
  const unsigned short* w1t[2];
  const unsigned short* w2t[2];
  const unsigned short* w3t[2];
  const void* b1[2];
  const void* b2[2];
  const void* b3[2];
  const void* w4[2];
  const void* b4[2];
  const int* counts;
  const int* perm;
  const int* flag;
  void* out;
};

// ---- dtype sniff: low short of each 4-byte group. bf16 data -> valid exps;
// fp32 data -> random mantissa bits, ~9% in-range. ----
__global__ void sniff_kernel(const void* obs, int* flag){
  int lane = threadIdx.x;
  unsigned short u = ((const unsigned short*)obs)[lane * 2];
  int e = (u >> 7) & 0xFF;
  int ok = (e >= 110 && e <= 132) ? 1 : 0;
  unsigned long long m = __ballot(ok);
  if (lane == 0) flag[0] = (__popcll(m) >= 32) ? 1 : 0;
}

__device__ __forceinline__ float ldval(const void* p, int idx, int isbf16){
  return isbf16 ? bf2f(((const unsigned short*)p)[idx]) : ((const float*)p)[idx];
}

// ---- weight prep: [t][k][n] -> bf16 [t][n][k], W1 K padded 264->288 ----
__global__ void prep_kernel(const void* q1W1, const void* q1W2, const void* q1W3,
                            const void* q2W1, const void* q2W2, const void* q2W3,
                            const int* flag, unsigned short* out){
  int isbf16 = flag[0];
  int gid = blockIdx.x * 256 + threadIdx.x;
  int net = gid / 614400;
  if (net >= 2) return;
  int idx = gid - net * 614400;
  const void* W1 = net ? q2W1 : q1W1;
  const void* W2 = net ? q2W2 : q1W2;
  const void* W3 = net ? q2W3 : q1W3;
  unsigned short* o = out + net * 614400;
  float v = 0.f;
  if (idx < 221184) {                      // W1t: [3][256][288]
    int t = idx / 73728; int rem = idx - t * 73728;
    int n = rem / 288;   int k = rem - n * 288;
    v = (k < 264) ? ldval(W1, (t * 264 + k) * 256 + n, isbf16) : 0.f;
  } else if (idx < 417792) {               // W2t: [3][256][256]
    int j = idx - 221184;
    int t = j >> 16; int rem = j & 65535;
    int n = rem >> 8; int k = rem & 255;
    v = ldval(W2, (t << 16) + (k << 8) + n, isbf16);
  } else {                                 // W3t: [3][256][256]
    int j = idx - 417792;
    int t = j >> 16; int rem = j & 65535;
    int n = rem >> 8; int k = rem & 255;
    v = ldval(W3, (t << 16) + (k << 8) + n, isbf16);
  }
  o[idx] = f2bf(v);
}

// ---- routing: EXACT input precision (downcast could flip argmax) ----
__device__ __forceinline__ int task_of(const void* obs, int b, int isbf16){
  float v0 = ldval(obs, b * 256 + 253, isbf16);
  float v1 = ldval(obs, b * 256 + 254, isbf16);
  float v2 = ldval(obs, b * 256 + 255, isbf16);
  int t = 0; float m = v0;
  if (v1 > m) { m = v1; t = 1; }   // strict > => first-occurrence argmax (jnp)
  if (v2 > m) { t = 2; }
  return t;
}

// per-block LDS histogram; 3 global atomics per block; cache task bytes
__global__ void route_count(const void* __restrict__ obs, const int* flag,
                            int* counts, unsigned char* tasks){
  __shared__ int h[3];
  int tid = threadIdx.x;
  if (tid < 3) h[tid] = 0;
  __syncthreads();
  int b = blockIdx.x * 256 + tid;
  int t = task_of(obs, b, flag[0]);
  tasks[b] = (unsigned char)t;
  atomicAdd(&h[t], 1);                 // LDS atomic, intra-block
  __syncthreads();
  if (tid < 3) atomicAdd(&counts[tid], h[tid]);
}

// block reserves a chunk per task (3 global atomics/block), LDS ranks
__global__ void route_scatter(const unsigned char* __restrict__ tasks,
                              const int* counts, int* cursors, int* perm){
  __shared__ int h[3], base[3];
  int tid = threadIdx.x;
  if (tid < 3) h[tid] = 0;
  __syncthreads();
  int b = blockIdx.x * 256 + tid;
  int t = tasks[b];
  int r = atomicAdd(&h[t], 1);         // rank within block AND block count
  __syncthreads();
  if (tid < 3) {
    int c0 = counts[0], c1 = counts[1];
    int segoff = (tid == 0) ? 0 : (tid == 1) ? ((c0 + 63) & ~63)
                                             : ((c0 + 63) & ~63) + ((c1 + 63) & ~63);
    base[tid] = segoff + atomicAdd(&cursors[tid], h[tid]);
  }
  __syncthreads();
  perm[base[t] + r] = b;
}

// ---- fused 4-layer routed MLP, one 64-row task-uniform tile per block ----
__global__ __launch_bounds__(256, 2) void fused_kernel(KParams p){
  __shared__ unsigned short X[64 * XSTR];   // 37,888 B ; reused as HB after layer 1
  __shared__ unsigned short HA[64 * HSTR];  // 33,792 B
  unsigned short* HB = X;

  int tid = threadIdx.x;
  int net = blockIdx.y;
  int p0  = blockIdx.x * 64;
  int isbf16 = p.flag[0];
  int c0 = p.counts[0], c1 = p.counts[1];
  int off1 = (c0 + 63) & ~63;
  int off2 = off1 + ((c1 + 63) & ~63);
  int task = (p0 >= off2) ? 2 : ((p0 >= off1) ? 1 : 0);

  // stage X tile: 64 rows x 33 chunks of 8 elements (32 obs + 1 action chunk)
  for (int idx = tid; idx < 64 * 33; idx += 256) {
    int row = idx / 33; int c = idx - row * 33;
    int r = p.perm[p0 + row];
    short8 sv = {0,0,0,0,0,0,0,0};
    if (r >= 0) {
      if (isbf16) {
        const unsigned short* src = (c < 32) ? ((const unsigned short*)p.obs + r * 256 + c * 8)
                                             : ((const unsigned short*)p.act + r * 8);
        sv = *(const short8*)src;
      } else {
        const float* src = (c < 32) ? ((const float*)p.obs + r * 256 + c * 8)
                                    : ((const float*)p.act + r * 8);
        f32x4 a = *(const f32x4*)src;
        f32x4 b = *(const f32x4*)(src + 4);
        #pragma unroll
        for (int j = 0; j < 4; j++) { sv[j] = (short)f2bf(a[j]); sv[4 + j] = (short)f2bf(b[j]); }
      }
    }
    *(short8*)(X + row * XSTR + c * 8) = sv;
  }
  // zero K-pad cols 264..287
  for (int idx = tid; idx < 64 * 3; idx += 256) {
    int row = idx / 3; int c = idx - row * 3;
    short8 z = {0,0,0,0,0,0,0,0};
    *(short8*)(X + row * XSTR + 264 + c * 8) = z;
  }
  __syncthreads();

  int wave = tid >> 6, lane = tid & 63, quad = lane >> 4, l16 = lane & 15;
  int nbase = wave * 64;   // each wave owns 64 output cols

  auto run_layer = [&](const unsigned short* lin, int lstride,
                       const unsigned short* wt, int K,
                       const void* bias, unsigned short* lout){
    f32x4 acc[4][4];
    f32x4 z = {0.f, 0.f, 0.f, 0.f};
    for (int mt = 0; mt < 4; mt++) for (int nt = 0; nt < 4; nt++) acc[mt][nt] = z;
    int kc = K >> 5;
    for (int kb = 0; kb < kc; ++kb) {
      int ko = (kb << 5) + quad * 8;
      short8 bfr[4], afr[4];
      #pragma unroll
      for (int nt = 0; nt < 4; nt++)          // B-frags from global (L2-hot)
        bfr[nt] = *(const short8*)(wt + (nbase + nt * 16 + l16) * K + ko);
      #pragma unroll
      for (int mt = 0; mt < 4; mt++)          // A-frags from LDS
        afr[mt] = *(const short8*)(lin + (mt * 16 + l16) * lstride + ko);
      #pragma unroll
      for (int mt = 0; mt < 4; mt++)
        #pragma unroll
        for (int nt = 0; nt < 4; nt++)
          acc[mt][nt] = __builtin_amdgcn_mfma_f32_16x16x32_bf16(afr[mt], bfr[nt], acc[mt][nt], 0, 0, 0);
    }
    float bv[4];
    #pragma unroll
    for (int nt = 0; nt < 4; nt++) bv[nt] = ldval(bias, nbase + nt * 16 + l16, isbf16);
    #pragma unroll
    for (int mt = 0; mt < 4; mt++)
      #pragma unroll
      for (int nt = 0; nt < 4; nt++) {
        f32x4 a = acc[mt][nt];
        #pragma unroll
        for (int r = 0; r < 4; r++) {
          float v = fmaxf(a[r] + bv[nt], 0.f);   // C/D: col=lane&15, row=quad*4+r
          lout[(mt * 16 + quad * 4 + r) * HSTR + nbase + nt * 16 + l16] = f2bf(v);
        }
      }
    __syncthreads();
  };

  run_layer(X,  XSTR, p.w1t[net] + task * 73728, 288, (const char*)p.b1[net] + task * 256 * (isbf16 ? 2 : 4), HA);
  run_layer(HA, HSTR, p.w2t[net] + task * 65536, 256, (const char*)p.b2[net] + task * 256 * (isbf16 ? 2 : 4), HB);
  run_layer(HB, HSTR, p.w3t[net] + task * 65536, 256, (const char*)p.b3[net] + task * 256 * (isbf16 ? 2 : 4), HA);

  // layer 4: y = h3 . w4 + b4  (4 threads per row, shuffle-combine)
  int row = tid >> 2, seg = tid & 3;
  float s = 0.f;
  #pragma unroll
  for (int kk = 0; kk < 64; kk += 8) {
    short8 hv = *(const short8*)(HA + row * HSTR + seg * 64 + kk);
    float wv[8];
    if (isbf16) {
      const unsigned short* w4p = (const unsigned short*)p.w4[net] + task * 256 + seg * 64 + kk;
      short8 t = *(const short8*)w4p;
      #pragma unroll
      for (int j = 0; j < 8; j++) wv[j] = bf2f((unsigned short)t[j]);
    } else {
      const float* w4p = (const float*)p.w4[net] + task * 256 + seg * 64 + kk;
      f32x4 a = *(const f32x4*)w4p;
      f32x4 b = *(const f32x4*)(w4p + 4);
      #pragma unroll
      for (int j = 0; j < 4; j++) { wv[j] = a[j]; wv[4 + j] = b[j]; }
    }
    #pragma unroll
    for (int j = 0; j < 8; j++)
      s += bf2f((unsigned short)hv[j]) * wv[j];
  }
  s += __shfl_xor(s, 1);
  s += __shfl_xor(s, 2);
  if (seg == 0) {
    int r = p.perm[p0 + row];
    if (r >= 0) {
      float y = s + ldval(p.b4[net], task, isbf16);
      if (isbf16) ((unsigned short*)p.out)[net * NB + r] = f2bf(y);
      else        ((float*)p.out)[net * NB + r] = y;
    }
  }
}

extern "C" void kernel_launch(void* const* d_in, const int* in_sizes, int n_in,
                              void* d_out, int out_size, void* d_ws, size_t ws_size,
                              hipStream_t stream) {
  char* ws = (char*)d_ws;
  int* counts  = (int*)ws;                   // 3 ints @0
  int* cursors = (int*)(ws + 16);            // 3 ints @16
  int* flag    = (int*)(ws + 48);            // 1 int  @48
  int* perm    = (int*)(ws + 64);            // 65728 ints
  unsigned char* tasks = (unsigned char*)(ws + 263168);  // 65536 bytes
  unsigned short* wts  = (unsigned short*)(ws + 328704); // 2 * 614400 bf16

  hipMemsetAsync(ws, 0, 64, stream);                 // counts + cursors + flag
  hipMemsetAsync(perm, 0xFF, 65728 * 4, stream);     // perm = -1 (pad sentinel)

  const void* obs = d_in[0];
  const void* act = d_in[1];

  sniff_kernel<<<1, 64, 0, stream>>>(obs, flag);
  prep_kernel<<<4800, 256, 0, stream>>>(d_in[2], d_in[4], d_in[6],
                                        d_in[10], d_in[12], d_in[14], flag, wts);
  route_count<<<256, 256, 0, stream>>>(obs, flag, counts, tasks);
  route_scatter<<<256, 256, 0, stream>>>(tasks, counts, cursors, perm);

  KParams kp;
  kp.obs = obs; kp.act = act;
  for (int q = 0; q < 2; q++) {
    int base = 2 + q * 8;
    kp.b1[q] = d_in[base + 1];
    kp.b2[q] = d_in[base + 3];
    kp.b3[q] = d_in[base + 5];
    kp.w4[q] = d_in[base + 6];
    kp.b4[q] = d_in[base + 7];
    kp.w1t[q] = wts + q * 614400;
    kp.w2t[q] = wts + q * 614400 + 221184;
    kp.w3t[q] = wts + q * 614400 + 417792;
  }
  kp.counts = counts; kp.perm = perm; kp.flag = flag;
  kp.out = d_out;

  fused_kernel<<<dim3(1027, 2), 256, 0, stream>>>(kp);
}

// Round 4
// 283.918 us; speedup vs baseline: 3.9348x; 1.0147x over previous
//
#include <hip/hip_runtime.h>
#include <hip/hip_bf16.h>

// R3 post-mortem: routing fixed (as predicted). fused_kernel now dominant:
// MfmaUtil 13 / VALUBusy 14 / HBM 6% / Occ 20% => latency-serialized K-loop
// (B-frags stream from L2/L3 ~600cyc, no pipelining, 8 waves/CU can't hide).
// R4: register double-buffered K-loop, coalesced-read prep, independent-load
// staging.

#define NB 65536
#define XSTR 296   // LDS row stride (shorts) for X buffer
#define HSTR 264   // LDS row stride (shorts) for H buffers

typedef __attribute__((ext_vector_type(8))) short short8;
typedef __attribute__((ext_vector_type(4))) short short4v;
typedef __attribute__((ext_vector_type(4))) float f32x4;

__device__ __forceinline__ float bf2f(unsigned short u){
  union { unsigned int i; float f; } x; x.i = ((unsigned int)u) << 16; return x.f;
}
__device__ __forceinline__ unsigned short f2bf(float f){
  unsigned int x = __float_as_uint(f);
  x += 0x7fffu + ((x >> 16) & 1u);   // RNE
  return (unsigned short)(x >> 16);
}

struct KParams {
  const void* obs;
  const void* act;
  const unsigned short* w1t[2];
  const unsigned short* w2t[2];
  const unsigned short* w3t[2];
  const void* b1[2];
  const void* b2[2];
  const void* b3[2];
  const void* w4[2];
  const void* b4[2];
  const int* counts;
  const int* perm;
  const int* flag;
  void* out;
};

// ---- dtype sniff ----
__global__ void sniff_kernel(const void* obs, int* flag){
  int lane = threadIdx.x;
  unsigned short u = ((const unsigned short*)obs)[lane * 2];
  int e = (u >> 7) & 0xFF;
  int ok = (e >= 110 && e <= 132) ? 1 : 0;
  unsigned long long m = __ballot(ok);
  if (lane == 0) flag[0] = (__popcll(m) >= 32) ? 1 : 0;
}

__device__ __forceinline__ float ldval(const void* p, int idx, int isbf16){
  return isbf16 ? bf2f(((const unsigned short*)p)[idx]) : ((const float*)p)[idx];
}

// ---- weight prep: coalesced READS (consecutive n), scattered writes ----
__global__ void prep_kernel(const void* q1W1, const void* q1W2, const void* q1W3,
                            const void* q2W1, const void* q2W2, const void* q2W3,
                            const int* flag, unsigned short* out){
  int isbf16 = flag[0];
  int gid = blockIdx.x * 256 + threadIdx.x;
  int net = gid / 614400;
  if (net >= 2) return;
  int idx = gid - net * 614400;
  const void* W1 = net ? q2W1 : q1W1;
  const void* W2 = net ? q2W2 : q1W2;
  const void* W3 = net ? q2W3 : q1W3;
  unsigned short* o = out + net * 614400;
  if (idx < 202752) {                 // W1 copy: src [t][k][n], idx=(t*264+k)*256+n
    int n = idx & 255;
    int tk = idx >> 8;
    int t = tk / 264, k = tk - t * 264;
    o[t * 73728 + n * 288 + k] = f2bf(ldval(W1, idx, isbf16));
  } else if (idx < 221184) {          // W1 K-pad zero (k=264..287)
    int j = idx - 202752;
    int t = j / 6144; int rem = j - t * 6144;
    int n = rem / 24; int k = 264 + (rem - n * 24);
    o[t * 73728 + n * 288 + k] = 0;
  } else if (idx < 417792) {          // W2: j = t*65536 + k*256 + n
    int j = idx - 221184;
    int n = j & 255; int k = (j >> 8) & 255; int t = j >> 16;
    o[221184 + t * 65536 + n * 256 + k] = f2bf(ldval(W2, j, isbf16));
  } else {                            // W3
    int j = idx - 417792;
    int n = j & 255; int k = (j >> 8) & 255; int t = j >> 16;
    o[417792 + t * 65536 + n * 256 + k] = f2bf(ldval(W3, j, isbf16));
  }
}

// ---- routing: exact input precision, one vector load ----
__device__ __forceinline__ int task_of(const void* obs, int b, int isbf16){
  float v0, v1, v2;
  if (isbf16) {
    const unsigned short* p = (const unsigned short*)obs + b * 256 + 252; // 8B-aligned
    short4v u = *(const short4v*)p;
    v0 = bf2f((unsigned short)u[1]); v1 = bf2f((unsigned short)u[2]); v2 = bf2f((unsigned short)u[3]);
  } else {
    const float* p = (const float*)obs + b * 256 + 252;                   // 16B-aligned
    f32x4 u = *(const f32x4*)p;
    v0 = u[1]; v1 = u[2]; v2 = u[3];
  }
  int t = 0; float m = v0;
  if (v1 > m) { m = v1; t = 1; }   // strict > => first-occurrence argmax (jnp)
  if (v2 > m) { t = 2; }
  return t;
}

__global__ void route_count(const void* __restrict__ obs, const int* flag,
                            int* counts, unsigned char* tasks){
  __shared__ int h[3];
  int tid = threadIdx.x;
  if (tid < 3) h[tid] = 0;
  __syncthreads();
  int b = blockIdx.x * 256 + tid;
  int t = task_of(obs, b, flag[0]);
  tasks[b] = (unsigned char)t;
  atomicAdd(&h[t], 1);
  __syncthreads();
  if (tid < 3) atomicAdd(&counts[tid], h[tid]);
}

__global__ void route_scatter(const unsigned char* __restrict__ tasks,
                              const int* counts, int* cursors, int* perm){
  __shared__ int h[3], base[3];
  int tid = threadIdx.x;
  if (tid < 3) h[tid] = 0;
  __syncthreads();
  int b = blockIdx.x * 256 + tid;
  int t = tasks[b];
  int r = atomicAdd(&h[t], 1);
  __syncthreads();
  if (tid < 3) {
    int c0 = counts[0], c1 = counts[1];
    int segoff = (tid == 0) ? 0 : (tid == 1) ? ((c0 + 63) & ~63)
                                             : ((c0 + 63) & ~63) + ((c1 + 63) & ~63);
    base[tid] = segoff + atomicAdd(&cursors[tid], h[tid]);
  }
  __syncthreads();
  perm[base[t] + r] = b;
}

// ---- fused 4-layer routed MLP, one 64-row task-uniform tile per block ----
__global__ __launch_bounds__(256, 2) void fused_kernel(KParams p){
  __shared__ unsigned short X[64 * XSTR];   // 37,888 B ; reused as HB after layer 1
  __shared__ unsigned short HA[64 * HSTR];  // 33,792 B
  unsigned short* HB = X;

  int tid = threadIdx.x;
  int net = blockIdx.y;
  int p0  = blockIdx.x * 64;
  int isbf16 = p.flag[0];
  int c0 = p.counts[0], c1 = p.counts[1];
  int off1 = (c0 + 63) & ~63;
  int off2 = off1 + ((c1 + 63) & ~63);
  int task = (p0 >= off2) ? 2 : ((p0 >= off1) ? 1 : 0);

  // stage X: 4 threads per row; 1 perm load then 8-9 INDEPENDENT global loads
  {
    int srow = tid >> 2, seg = tid & 3;
    int r = p.perm[p0 + srow];
    #pragma unroll
    for (int j = 0; j < 9; ++j) {
      int c = seg + 4 * j;
      if (c < 33) {
        short8 sv = {0,0,0,0,0,0,0,0};
        if (r >= 0) {
          if (isbf16) {
            const unsigned short* src = (c < 32) ? ((const unsigned short*)p.obs + r * 256 + c * 8)
                                                 : ((const unsigned short*)p.act + r * 8);
            sv = *(const short8*)src;
          } else {
            const float* src = (c < 32) ? ((const float*)p.obs + r * 256 + c * 8)
                                        : ((const float*)p.act + r * 8);
            f32x4 a = *(const f32x4*)src;
            f32x4 b = *(const f32x4*)(src + 4);
            #pragma unroll
            for (int q = 0; q < 4; q++) { sv[q] = (short)f2bf(a[q]); sv[4 + q] = (short)f2bf(b[q]); }
          }
        }
        *(short8*)(X + srow * XSTR + c * 8) = sv;
      }
    }
    if (seg < 3) {                       // zero K-pad cols 264..287 (chunks 33..35)
      short8 z = {0,0,0,0,0,0,0,0};
      *(short8*)(X + srow * XSTR + (33 + seg) * 8) = z;
    }
  }
  __syncthreads();

  int wave = tid >> 6, lane = tid & 63, quad = lane >> 4, l16 = lane & 15;
  int nbase = wave * 64;   // each wave owns 64 output cols

  auto run_layer = [&](const unsigned short* lin, int lstride,
                       const unsigned short* wt, int K,
                       const void* bias, unsigned short* lout){
    f32x4 acc[4][4];
    f32x4 zz = {0.f, 0.f, 0.f, 0.f};
    #pragma unroll
    for (int mt = 0; mt < 4; mt++)
      #pragma unroll
      for (int nt = 0; nt < 4; nt++) acc[mt][nt] = zz;
    const int kc = K >> 5;
    short8 bfr[2][4], afr[2][4];
    {   // prologue: chunk 0
      int ko = quad * 8;
      #pragma unroll
      for (int nt = 0; nt < 4; nt++)
        bfr[0][nt] = *(const short8*)(wt + (nbase + nt * 16 + l16) * K + ko);
      #pragma unroll
      for (int mt = 0; mt < 4; mt++)
        afr[0][mt] = *(const short8*)(lin + (mt * 16 + l16) * lstride + ko);
    }
    #pragma unroll
    for (int kb = 0; kb < kc; ++kb) {
      int cur = kb & 1, nxt = cur ^ 1;
      if (kb + 1 < kc) {   // prefetch chunk kb+1 during chunk kb's MFMA
        int ko = ((kb + 1) << 5) + quad * 8;
        #pragma unroll
        for (int nt = 0; nt < 4; nt++)
          bfr[nxt][nt] = *(const short8*)(wt + (nbase + nt * 16 + l16) * K + ko);
        #pragma unroll
        for (int mt = 0; mt < 4; mt++)
          afr[nxt][mt] = *(const short8*)(lin + (mt * 16 + l16) * lstride + ko);
      }
      #pragma unroll
      for (int mt = 0; mt < 4; mt++)
        #pragma unroll
        for (int nt = 0; nt < 4; nt++)
          acc[mt][nt] = __builtin_amdgcn_mfma_f32_16x16x32_bf16(afr[cur][mt], bfr[cur][nt], acc[mt][nt], 0, 0, 0);
    }
    float bv[4];
    #pragma unroll
    for (int nt = 0; nt < 4; nt++) bv[nt] = ldval(bias, nbase + nt * 16 + l16, isbf16);
    #pragma unroll
    for (int mt = 0; mt < 4; mt++)
      #pragma unroll
      for (int nt = 0; nt < 4; nt++) {
        f32x4 a = acc[mt][nt];
        #pragma unroll
        for (int r = 0; r < 4; r++) {
          float v = fmaxf(a[r] + bv[nt], 0.f);   // C/D: col=lane&15, row=quad*4+r
          lout[(mt * 16 + quad * 4 + r) * HSTR + nbase + nt * 16 + l16] = f2bf(v);
        }
      }
    __syncthreads();
  };

  run_layer(X,  XSTR, p.w1t[net] + task * 73728, 288, (const char*)p.b1[net] + task * 256 * (isbf16 ? 2 : 4), HA);
  run_layer(HA, HSTR, p.w2t[net] + task * 65536, 256, (const char*)p.b2[net] + task * 256 * (isbf16 ? 2 : 4), HB);
  run_layer(HB, HSTR, p.w3t[net] + task * 65536, 256, (const char*)p.b3[net] + task * 256 * (isbf16 ? 2 : 4), HA);

  // layer 4: y = h3 . w4 + b4  (4 threads per row, shuffle-combine)
  int row = tid >> 2, seg = tid & 3;
  float s = 0.f;
  #pragma unroll
  for (int kk = 0; kk < 64; kk += 8) {
    short8 hv = *(const short8*)(HA + row * HSTR + seg * 64 + kk);
    float wv[8];
    if (isbf16) {
      const unsigned short* w4p = (const unsigned short*)p.w4[net] + task * 256 + seg * 64 + kk;
      short8 t = *(const short8*)w4p;
      #pragma unroll
      for (int j = 0; j < 8; j++) wv[j] = bf2f((unsigned short)t[j]);
    } else {
      const float* w4p = (const float*)p.w4[net] + task * 256 + seg * 64 + kk;
      f32x4 a = *(const f32x4*)w4p;
      f32x4 b = *(const f32x4*)(w4p + 4);
      #pragma unroll
      for (int j = 0; j < 4; j++) { wv[j] = a[j]; wv[4 + j] = b[j]; }
    }
    #pragma unroll
    for (int j = 0; j < 8; j++)
      s += bf2f((unsigned short)hv[j]) * wv[j];
  }
  s += __shfl_xor(s, 1);
  s += __shfl_xor(s, 2);
  if (seg == 0) {
    int r = p.perm[p0 + row];
    if (r >= 0) {
      float y = s + ldval(p.b4[net], task, isbf16);
      if (isbf16) ((unsigned short*)p.out)[net * NB + r] = f2bf(y);
      else        ((float*)p.out)[net * NB + r] = y;
    }
  }
}

extern "C" void kernel_launch(void* const* d_in, const int* in_sizes, int n_in,
                              void* d_out, int out_size, void* d_ws, size_t ws_size,
                              hipStream_t stream) {
  char* ws = (char*)d_ws;
  int* counts  = (int*)ws;                   // 3 ints @0
  int* cursors = (int*)(ws + 16);            // 3 ints @16
  int* flag    = (int*)(ws + 48);            // 1 int  @48
  int* perm    = (int*)(ws + 64);            // 65728 ints
  unsigned char* tasks = (unsigned char*)(ws + 263168);  // 65536 bytes
  unsigned short* wts  = (unsigned short*)(ws + 328704); // 2 * 614400 bf16

  hipMemsetAsync(ws, 0, 64, stream);                 // counts + cursors + flag
  hipMemsetAsync(perm, 0xFF, 65728 * 4, stream);     // perm = -1 (pad sentinel)

  const void* obs = d_in[0];
  const void* act = d_in[1];

  sniff_kernel<<<1, 64, 0, stream>>>(obs, flag);
  prep_kernel<<<4800, 256, 0, stream>>>(d_in[2], d_in[4], d_in[6],
                                        d_in[10], d_in[12], d_in[14], flag, wts);
  route_count<<<256, 256, 0, stream>>>(obs, flag, counts, tasks);
  route_scatter<<<256, 256, 0, stream>>>(tasks, counts, cursors, perm);

  KParams kp;
  kp.obs = obs; kp.act = act;
  for (int q = 0; q < 2; q++) {
    int base = 2 + q * 8;
    kp.b1[q] = d_in[base + 1];
    kp.b2[q] = d_in[base + 3];
    kp.b3[q] = d_in[base + 5];
    kp.w4[q] = d_in[base + 6];
    kp.b4[q] = d_in[base + 7];
    kp.w1t[q] = wts + q * 614400;
    kp.w2t[q] = wts + q * 614400 + 221184;
    kp.w3t[q] = wts + q * 614400 + 417792;
  }
  kp.counts = counts; kp.perm = perm; kp.flag = flag;
  kp.out = d_out;

  fused_kernel<<<dim3(1027, 2), 256, 0, stream>>>(kp);
}